// Round 11
// baseline (147.446 us; speedup 1.0000x reference)
//
#include <hip/hip_runtime.h>
#include <cstdint>

// Shapes fixed by the harness:
// u, delta, z: (b=2, d=1024, l=2048) fp32; A: (d, n=16); B, C: (b, n, l); D: (d,)
constexpr int kD = 1024;
constexpr int kN = 16;
constexpr int kL = 2048;
constexpr int BLOCK = 256;       // R11: half the threads, T=8 -> chip-wide scan work halves
constexpr int T  = kL / BLOCK;   // 8 timesteps per thread
constexpr int NW = BLOCK / 64;   // 4 waves per block
constexpr int NH = 8;            // states per half (kN/2)
constexpr float LOG2E = 1.44269504088896340736f;

__device__ __forceinline__ float fast_exp2(float x) { return __builtin_amdgcn_exp2f(x); }
__device__ __forceinline__ float fast_exp(float x)  { return __builtin_amdgcn_exp2f(x * LOG2E); }
__device__ __forceinline__ float softplus_f(float x) {
  return (x > 20.0f) ? x : __logf(1.0f + fast_exp(x));
}

// DPP move: result = valid&row-enabled ? src[shifted lane] : old.
// Scan steps pass the combine identity as 'old' so masked lanes are no-ops.
template<int CTRL, int RM>
__device__ __forceinline__ float dppf(float old_, float src) {
  union U { float f; int i; };
  U o, s, r; o.f = old_; s.f = src;
  r.i = __builtin_amdgcn_update_dpp(o.i, s.i, CTRL, RM, 0xF, false);
  return r.f;
}

// 64-lane inclusive scan of (a,x) entirely on the VALU pipe (gfx9 DPP:
// row_shr 1/2/4/8, row_bcast15 rows{1,3}, row_bcast31 rows{2,3}).
// Combine: (a1,x1)*(a2,x2) = (a1*a2, a2*x1+x2).  [R9: -20 us vs ds_bpermute]
__device__ __forceinline__ void wave_scan(float& a, float& x) {
  { float as = dppf<0x111,0xF>(1.0f,a); float xs = dppf<0x111,0xF>(0.0f,x); x = a*xs + x; a = as*a; }
  { float as = dppf<0x112,0xF>(1.0f,a); float xs = dppf<0x112,0xF>(0.0f,x); x = a*xs + x; a = as*a; }
  { float as = dppf<0x114,0xF>(1.0f,a); float xs = dppf<0x114,0xF>(0.0f,x); x = a*xs + x; a = as*a; }
  { float as = dppf<0x118,0xF>(1.0f,a); float xs = dppf<0x118,0xF>(0.0f,x); x = a*xs + x; a = as*a; }
  { float as = dppf<0x142,0xA>(1.0f,a); float xs = dppf<0x142,0xA>(0.0f,x); x = a*xs + x; a = as*a; }
  { float as = dppf<0x143,0xC>(1.0f,a); float xs = dppf<0x143,0xC>(0.0f,x); x = a*xs + x; a = as*a; }
}

// Single-arg launch_bounds ONLY: any min-waves hint triggers a spill cascade
// (R2: 48 VGPR + 350 MB scratch; R3: 64 VGPR + 260 MB; R6: 1024-thr cap).
// 256-thread block -> 256-VGPR ceiling; ~140 live regs fits without spill.
__global__ __launch_bounds__(BLOCK)
void selscan_kernel(const float* __restrict__ u,  const float* __restrict__ dl,
                    const float* __restrict__ A,  const float* __restrict__ Bm,
                    const float* __restrict__ Cm, const float* __restrict__ Dv,
                    const float* __restrict__ zm, float* __restrict__ out)
{
  const int row  = blockIdx.x;          // b*kD + d
  const int b    = row >> 10;           // kD = 1024
  const int d    = row & (kD - 1);
  const int tid  = threadIdx.x;
  const int lane = tid & 63;
  const int wid  = tid >> 6;

  const size_t roff = (size_t)row * kL;
  const float4* u4 = reinterpret_cast<const float4*>(u  + roff);
  const float4* d4 = reinterpret_cast<const float4*>(dl + roff);

  // Per-thread chunk [tid*T, tid*T+T): u, softplus(delta), delta*u in regs.
  float uu[T], sp[T], du[T];
  {
    float4 a0 = u4[tid*2+0], a1 = u4[tid*2+1];
    uu[0]=a0.x; uu[1]=a0.y; uu[2]=a0.z; uu[3]=a0.w;
    uu[4]=a1.x; uu[5]=a1.y; uu[6]=a1.z; uu[7]=a1.w;
    float4 b0 = d4[tid*2+0], b1 = d4[tid*2+1];
    float dv[T] = {b0.x,b0.y,b0.z,b0.w,b1.x,b1.y,b1.z,b1.w};
    #pragma unroll
    for (int i = 0; i < T; ++i) { sp[i] = softplus_f(dv[i]); du[i] = sp[i] * uu[i]; }
  }

  float y[T];
  #pragma unroll
  for (int i = 0; i < T; ++i) y[i] = 0.0f;

  __shared__ float sA[NW][NH], sX[NW][NH], eX[NW][NH];

  #pragma unroll 1                      // halves sequential: live-range control
  for (int half = 0; half < 2; ++half) {
    float Ar[NH];
    {
      const float4* A4 = reinterpret_cast<const float4*>(A + (size_t)d * kN + half * NH);
      float4 v0 = A4[0], v1 = A4[1];
      Ar[0]=v0.x*LOG2E; Ar[1]=v0.y*LOG2E; Ar[2]=v0.z*LOG2E; Ar[3]=v0.w*LOG2E;
      Ar[4]=v1.x*LOG2E; Ar[5]=v1.y*LOG2E; Ar[6]=v1.z*LOG2E; Ar[7]=v1.w*LOG2E;
    }
    const float4* B4 = reinterpret_cast<const float4*>(Bm + ((size_t)b * kN + half * NH) * kL);
    const float4* C4 = reinterpret_cast<const float4*>(Cm + ((size_t)b * kN + half * NH) * kL);

    // ---- Pass A with the cp-trick: C consumed at load time.
    // h_i = pp_i*h0 + hl_i (linearity) =>  y_i += C_i*hl_i here,
    // cp_i = C_i*pp_i saved; post-scan apply is pure register FMA.
    float cp[NH][T];
    float cA[NH], cX[NH];
    #pragma unroll
    for (int n = 0; n < NH; ++n) {
      float4 b0 = B4[n*(kL/4) + tid*2 + 0];
      float4 b1 = B4[n*(kL/4) + tid*2 + 1];
      float4 c0 = C4[n*(kL/4) + tid*2 + 0];
      float4 c1 = C4[n*(kL/4) + tid*2 + 1];
      float Bv[T] = {b0.x,b0.y,b0.z,b0.w,b1.x,b1.y,b1.z,b1.w};
      float Cv[T] = {c0.x,c0.y,c0.z,c0.w,c1.x,c1.y,c1.z,c1.w};
      float h = 0.0f, p = 1.0f;
      #pragma unroll
      for (int i = 0; i < T; ++i) {
        float a = fast_exp2(sp[i] * Ar[n]);
        h = a * h + du[i] * Bv[i];
        p *= a;
        y[i] += Cv[i] * h;
        cp[n][i] = Cv[i] * p;
      }
      cA[n] = p; cX[n] = h;
    }

    // ---- Wave-level scan on chunk aggregates — DPP, zero DS-pipe ops.
    #pragma unroll
    for (int n = 0; n < NH; ++n) wave_scan(cA[n], cX[n]);

    // ---- Cross-wave scan (4 waves) through LDS (tiny DS traffic).
    if (lane == 63) {
      #pragma unroll
      for (int n = 0; n < NH; ++n) { sA[wid][n] = cA[n]; sX[wid][n] = cX[n]; }
    }
    __syncthreads();
    if (tid < NH) {
      const int n = tid;
      float x = 0.0f;
      #pragma unroll
      for (int w = 0; w < NW; ++w) {
        eX[w][n] = x;                    // exclusive x-prefix for wave w
        x = sA[w][n] * x + sX[w][n];
      }
    }
    __syncthreads();

    // ---- Apply: y_i += cp_i * h0   (pure FMA from registers)
    #pragma unroll
    for (int n = 0; n < NH; ++n) {
      // lane-exclusive prefix via wave_shr:1; lane0 gets the identity old.
      float al = dppf<0x138,0xF>(1.0f, cA[n]);
      float xl = dppf<0x138,0xF>(0.0f, cX[n]);
      float h0 = al * eX[wid][n] + xl;   // state entering this thread's chunk
      #pragma unroll
      for (int i = 0; i < T; ++i) y[i] += cp[n][i] * h0;
    }
    __syncthreads();   // protect sA/sX/eX reuse across halves
  }

  // ---- Epilogue: + u*D, * silu(z), store  (uu kept in regs)
  const float Dd = Dv[d];
  const float4* z4 = reinterpret_cast<const float4*>(zm + roff);
  float4 z0 = z4[tid*2+0], z1 = z4[tid*2+1];
  float zv[T] = {z0.x,z0.y,z0.z,z0.w,z1.x,z1.y,z1.z,z1.w};
  float ov[T];
  #pragma unroll
  for (int i = 0; i < T; ++i) {
    float yy  = y[i] + uu[i] * Dd;
    float sig = 1.0f / (1.0f + fast_exp(-zv[i]));
    ov[i] = yy * zv[i] * sig;
  }
  float4* out4 = reinterpret_cast<float4*>(out + roff);
  out4[tid*2+0] = make_float4(ov[0], ov[1], ov[2], ov[3]);
  out4[tid*2+1] = make_float4(ov[4], ov[5], ov[6], ov[7]);
}

extern "C" void kernel_launch(void* const* d_in, const int* in_sizes, int n_in,
                              void* d_out, int out_size, void* d_ws, size_t ws_size,
                              hipStream_t stream)
{
  const float* u  = (const float*)d_in[0];
  const float* dl = (const float*)d_in[1];
  const float* A  = (const float*)d_in[2];
  const float* Bm = (const float*)d_in[3];
  const float* Cm = (const float*)d_in[4];
  const float* Dv = (const float*)d_in[5];
  const float* zm = (const float*)d_in[6];
  float* out = (float*)d_out;
  const int rows = in_sizes[0] / kL;   // b*d = 2048
  selscan_kernel<<<rows, BLOCK, 0, stream>>>(u, dl, A, Bm, Cm, Dv, zm, out);
}

// Round 12
// 135.949 us; speedup vs baseline: 1.0846x; 1.0846x over previous
//
#include <hip/hip_runtime.h>
#include <cstdint>

// Shapes fixed by the harness:
// u, delta, z: (b=2, d=1024, l=2048) fp32; A: (d, n=16); B, C: (b, n, l); D: (d,)
constexpr int kD = 1024;
constexpr int kN = 16;
constexpr int kL = 2048;
constexpr int BLOCK = 512;
constexpr int T  = kL / BLOCK;   // 4 timesteps per thread (one float4)
constexpr int NW = BLOCK / 64;   // 8 waves per block
constexpr int NH = 8;            // states per half (kN/2)
constexpr float LOG2E = 1.44269504088896340736f;

__device__ __forceinline__ float fast_exp2(float x) { return __builtin_amdgcn_exp2f(x); }
__device__ __forceinline__ float fast_exp(float x)  { return __builtin_amdgcn_exp2f(x * LOG2E); }
__device__ __forceinline__ float softplus_f(float x) {
  return (x > 20.0f) ? x : __logf(1.0f + fast_exp(x));
}

// DPP move with explicit 'old' (identity) — used only for the cheap
// exclusive-prefix in the apply phase (16 uses/thread).
template<int CTRL, int RM>
__device__ __forceinline__ float dppf(float old_, float src) {
  union U { float f; int i; };
  U o, s, r; o.f = old_; s.f = src;
  r.i = __builtin_amdgcn_update_dpp(o.i, s.i, CTRL, RM, 0xF, false);
  return r.f;
}

// R12: the hot 64-lane scan in raw DPP asm. Hardware identity-select:
// bound_ctrl off + row_mask => invalid lanes DON'T WRITE dest, so in-place
//   v_fmac_f32_dpp x, x, a   (x += dpp(x)*a; boundary lanes keep x)
//   v_mul_f32_dpp  a, a, a   (a *= dpp(a);   boundary lanes keep a)
// is one masked Hillis-Steele step in 2 insts/state (was 6 via update_dpp:
// each identity-old costs a mov). State-inner interleave gives 16-inst
// spacing for the VALU-write->DPP-read hazard; s_nop 1 covers block entry.
#define SCAN_FM(X, A, CTRL) \
  "v_fmac_f32_dpp " X ", " X ", " A " " CTRL "\n\t" \
  "v_mul_f32_dpp "  A ", " A ", " A " " CTRL "\n\t"
#define SCAN_STEP(CTRL) \
  SCAN_FM("%0","%8",CTRL)  SCAN_FM("%1","%9",CTRL)  \
  SCAN_FM("%2","%10",CTRL) SCAN_FM("%3","%11",CTRL) \
  SCAN_FM("%4","%12",CTRL) SCAN_FM("%5","%13",CTRL) \
  SCAN_FM("%6","%14",CTRL) SCAN_FM("%7","%15",CTRL)

// Single-arg launch_bounds ONLY: any min-waves hint triggers a spill cascade
// (R2: 48 VGPR + 350 MB scratch; R3: 64 VGPR + 260 MB; R6: 1024-thr cap).
__global__ __launch_bounds__(BLOCK)
void selscan_kernel(const float* __restrict__ u,  const float* __restrict__ dl,
                    const float* __restrict__ A,  const float* __restrict__ Bm,
                    const float* __restrict__ Cm, const float* __restrict__ Dv,
                    const float* __restrict__ zm, float* __restrict__ out)
{
  const int row  = blockIdx.x;          // b*kD + d
  const int b    = row >> 10;           // kD = 1024
  const int d    = row & (kD - 1);
  const int tid  = threadIdx.x;
  const int lane = tid & 63;
  const int wid  = tid >> 6;

  const size_t roff = (size_t)row * kL;
  const float4* u4 = reinterpret_cast<const float4*>(u  + roff);
  const float4* d4 = reinterpret_cast<const float4*>(dl + roff);

  // Per-thread chunk [tid*T, tid*T+T): u, softplus(delta), delta*u in regs.
  float uu[T], sp[T], du[T];
  {
    float4 a0 = u4[tid];
    uu[0]=a0.x; uu[1]=a0.y; uu[2]=a0.z; uu[3]=a0.w;
    float4 b0 = d4[tid];
    float dv[T] = {b0.x, b0.y, b0.z, b0.w};
    #pragma unroll
    for (int i = 0; i < T; ++i) { sp[i] = softplus_f(dv[i]); du[i] = sp[i] * uu[i]; }
  }

  float y[T];
  #pragma unroll
  for (int i = 0; i < T; ++i) y[i] = 0.0f;

  __shared__ float sA[NW][NH], sX[NW][NH], eX[NW][NH];

  #pragma unroll 1                      // halves sequential: live-range control
  for (int half = 0; half < 2; ++half) {
    float Ar[NH];
    {
      const float4* A4 = reinterpret_cast<const float4*>(A + (size_t)d * kN + half * NH);
      float4 v0 = A4[0], v1 = A4[1];
      Ar[0]=v0.x*LOG2E; Ar[1]=v0.y*LOG2E; Ar[2]=v0.z*LOG2E; Ar[3]=v0.w*LOG2E;
      Ar[4]=v1.x*LOG2E; Ar[5]=v1.y*LOG2E; Ar[6]=v1.z*LOG2E; Ar[7]=v1.w*LOG2E;
    }
    const float4* B4 = reinterpret_cast<const float4*>(Bm + ((size_t)b * kN + half * NH) * kL);
    const float4* C4 = reinterpret_cast<const float4*>(Cm + ((size_t)b * kN + half * NH) * kL);

    // ---- Pass A with the cp-trick: C consumed at load time.
    // h_i = pp_i*h0 + hl_i (linearity) =>  y_i += C_i*hl_i here,
    // cp_i = C_i*pp_i saved; post-scan apply is pure register FMA.
    float cp[NH][T];
    float cA[NH], cX[NH];
    #pragma unroll
    for (int n = 0; n < NH; ++n) {
      float4 b0 = B4[n*(kL/4) + tid];
      float4 c0 = C4[n*(kL/4) + tid];
      float Bv[T] = {b0.x, b0.y, b0.z, b0.w};
      float Cv[T] = {c0.x, c0.y, c0.z, c0.w};
      float h = 0.0f, p = 1.0f;
      #pragma unroll
      for (int i = 0; i < T; ++i) {
        float a = fast_exp2(sp[i] * Ar[n]);
        h = a * h + du[i] * Bv[i];
        p *= a;
        y[i] += Cv[i] * h;
        cp[n][i] = Cv[i] * p;
      }
      cA[n] = p; cX[n] = h;
    }

    // ---- Wave-level scan on chunk aggregates — raw DPP, 2 inst/state/step.
    {
      float x0=cX[0], x1=cX[1], x2=cX[2], x3=cX[3],
            x4=cX[4], x5=cX[5], x6=cX[6], x7=cX[7];
      float a0=cA[0], a1=cA[1], a2=cA[2], a3=cA[3],
            a4=cA[4], a5=cA[5], a6=cA[6], a7=cA[7];
      asm("s_nop 1\n\t"
          SCAN_STEP("row_shr:1 row_mask:0xf bank_mask:0xf")
          SCAN_STEP("row_shr:2 row_mask:0xf bank_mask:0xf")
          SCAN_STEP("row_shr:4 row_mask:0xf bank_mask:0xf")
          SCAN_STEP("row_shr:8 row_mask:0xf bank_mask:0xf")
          SCAN_STEP("row_bcast:15 row_mask:0xa bank_mask:0xf")
          SCAN_STEP("row_bcast:31 row_mask:0xc bank_mask:0xf")
          : "+v"(x0), "+v"(x1), "+v"(x2), "+v"(x3),
            "+v"(x4), "+v"(x5), "+v"(x6), "+v"(x7),
            "+v"(a0), "+v"(a1), "+v"(a2), "+v"(a3),
            "+v"(a4), "+v"(a5), "+v"(a6), "+v"(a7));
      cX[0]=x0; cX[1]=x1; cX[2]=x2; cX[3]=x3;
      cX[4]=x4; cX[5]=x5; cX[6]=x6; cX[7]=x7;
      cA[0]=a0; cA[1]=a1; cA[2]=a2; cA[3]=a3;
      cA[4]=a4; cA[5]=a5; cA[6]=a6; cA[7]=a7;
    }

    // ---- Cross-wave scan (8 waves) through LDS (tiny DS traffic).
    if (lane == 63) {
      #pragma unroll
      for (int n = 0; n < NH; ++n) { sA[wid][n] = cA[n]; sX[wid][n] = cX[n]; }
    }
    __syncthreads();
    if (tid < NH) {
      const int n = tid;
      float x = 0.0f;
      #pragma unroll
      for (int w = 0; w < NW; ++w) {
        eX[w][n] = x;                    // exclusive x-prefix for wave w
        x = sA[w][n] * x + sX[w][n];
      }
    }
    __syncthreads();

    // ---- Apply: y_i += cp_i * h0   (pure FMA from registers)
    #pragma unroll
    for (int n = 0; n < NH; ++n) {
      // lane-exclusive prefix via wave_shr:1; lane0 gets the identity old.
      float al = dppf<0x138,0xF>(1.0f, cA[n]);
      float xl = dppf<0x138,0xF>(0.0f, cX[n]);
      float h0 = al * eX[wid][n] + xl;   // state entering this thread's chunk
      #pragma unroll
      for (int i = 0; i < T; ++i) y[i] += cp[n][i] * h0;
    }
    __syncthreads();   // protect sA/sX/eX reuse across halves
  }

  // ---- Epilogue: + u*D, * silu(z), store  (uu kept in regs)
  const float Dd = Dv[d];
  const float4* z4 = reinterpret_cast<const float4*>(zm + roff);
  float4 z0 = z4[tid];
  float zv[T] = {z0.x, z0.y, z0.z, z0.w};
  float ov[T];
  #pragma unroll
  for (int i = 0; i < T; ++i) {
    float yy  = y[i] + uu[i] * Dd;
    float sig = 1.0f / (1.0f + fast_exp(-zv[i]));
    ov[i] = yy * zv[i] * sig;
  }
  reinterpret_cast<float4*>(out + roff)[tid] = make_float4(ov[0], ov[1], ov[2], ov[3]);
}

extern "C" void kernel_launch(void* const* d_in, const int* in_sizes, int n_in,
                              void* d_out, int out_size, void* d_ws, size_t ws_size,
                              hipStream_t stream)
{
  const float* u  = (const float*)d_in[0];
  const float* dl = (const float*)d_in[1];
  const float* A  = (const float*)d_in[2];
  const float* Bm = (const float*)d_in[3];
  const float* Cm = (const float*)d_in[4];
  const float* Dv = (const float*)d_in[5];
  const float* zm = (const float*)d_in[6];
  float* out = (float*)d_out;
  const int rows = in_sizes[0] / kL;   // b*d = 2048
  selscan_kernel<<<rows, BLOCK, 0, stream>>>(u, dl, A, Bm, Cm, Dv, zm, out);
}

// Round 13
// 135.684 us; speedup vs baseline: 1.0867x; 1.0020x over previous
//
#include <hip/hip_runtime.h>
#include <cstdint>

// Shapes fixed by the harness:
// u, delta, z: (b=2, d=1024, l=2048) fp32; A: (d, n=16); B, C: (b, n, l); D: (d,)
constexpr int kD = 1024;
constexpr int kN = 16;
constexpr int kL = 2048;
constexpr int BLOCK = 512;
constexpr int T  = kL / BLOCK;   // 4 timesteps per thread (one float4)
constexpr int NW = BLOCK / 64;   // 8 waves per block
constexpr int NH = 8;            // states per half (kN/2)
constexpr float LOG2E = 1.44269504088896340736f;

__device__ __forceinline__ float fast_exp2(float x) { return __builtin_amdgcn_exp2f(x); }
__device__ __forceinline__ float fast_exp(float x)  { return __builtin_amdgcn_exp2f(x * LOG2E); }
__device__ __forceinline__ float softplus_f(float x) {
  return (x > 20.0f) ? x : __logf(1.0f + fast_exp(x));
}

// DPP move with explicit 'old' (identity) — used only for the lane-exclusive
// prefix in the apply phase (16 uses/thread).
template<int CTRL, int RM>
__device__ __forceinline__ float dppf(float old_, float src) {
  union U { float f; int i; };
  U o, s, r; o.f = old_; s.f = src;
  r.i = __builtin_amdgcn_update_dpp(o.i, s.i, CTRL, RM, 0xF, false);
  return r.f;
}

__device__ __forceinline__ float readlane_f(float v, int l) {
  union U { float f; int i; };
  U a, r; a.f = v;
  r.i = __builtin_amdgcn_readlane(a.i, l);
  return r.f;
}

// R12: hot 64-lane scan in raw DPP asm. bound_ctrl off + row_mask => invalid
// lanes DON'T WRITE dest, so in-place
//   v_fmac_f32_dpp x, x, a   (x += dpp(x)*a; boundary lanes keep x)
//   v_mul_f32_dpp  a, a, a   (a *= dpp(a);   boundary lanes keep a)
// is one masked Hillis-Steele step in 2 insts/state. State-inner interleave
// gives 16-inst spacing for the VALU->DPP hazard; s_nop 1 covers entry.
#define SCAN_FM(X, A, CTRL) \
  "v_fmac_f32_dpp " X ", " X ", " A " " CTRL "\n\t" \
  "v_mul_f32_dpp "  A ", " A ", " A " " CTRL "\n\t"
#define SCAN_STEP(CTRL) \
  SCAN_FM("%0","%8",CTRL)  SCAN_FM("%1","%9",CTRL)  \
  SCAN_FM("%2","%10",CTRL) SCAN_FM("%3","%11",CTRL) \
  SCAN_FM("%4","%12",CTRL) SCAN_FM("%5","%13",CTRL) \
  SCAN_FM("%6","%14",CTRL) SCAN_FM("%7","%15",CTRL)

// Single-arg launch_bounds ONLY: any min-waves hint triggers a spill cascade
// (R2: 48 VGPR + 350 MB scratch; R3: 64 VGPR + 260 MB; R6: 1024-thr cap).
__global__ __launch_bounds__(BLOCK)
void selscan_kernel(const float* __restrict__ u,  const float* __restrict__ dl,
                    const float* __restrict__ A,  const float* __restrict__ Bm,
                    const float* __restrict__ Cm, const float* __restrict__ Dv,
                    const float* __restrict__ zm, float* __restrict__ out)
{
  const int row  = blockIdx.x;          // b*kD + d
  const int b    = row >> 10;           // kD = 1024
  const int d    = row & (kD - 1);
  const int tid  = threadIdx.x;
  const int lane = tid & 63;
  const int wid  = tid >> 6;

  const size_t roff = (size_t)row * kL;
  const float4* u4 = reinterpret_cast<const float4*>(u  + roff);
  const float4* d4 = reinterpret_cast<const float4*>(dl + roff);

  // Per-thread chunk [tid*T, tid*T+T): u, softplus(delta), delta*u in regs.
  float uu[T], sp[T], du[T];
  {
    float4 a0 = u4[tid];
    uu[0]=a0.x; uu[1]=a0.y; uu[2]=a0.z; uu[3]=a0.w;
    float4 b0 = d4[tid];
    float dv[T] = {b0.x, b0.y, b0.z, b0.w};
    #pragma unroll
    for (int i = 0; i < T; ++i) { sp[i] = softplus_f(dv[i]); du[i] = sp[i] * uu[i]; }
  }

  float y[T];
  #pragma unroll
  for (int i = 0; i < T; ++i) y[i] = 0.0f;

  // Per-half wave-total buffers: (a,x) per (wave, state). 2*8*8*8B = 1 KB.
  // Separate buffer per half -> no end-of-half barrier needed.
  __shared__ float2 sAX[2][NW][NH];

  #pragma unroll 1                      // halves sequential: live-range control
  for (int half = 0; half < 2; ++half) {
    float Ar[NH];
    {
      const float4* A4 = reinterpret_cast<const float4*>(A + (size_t)d * kN + half * NH);
      float4 v0 = A4[0], v1 = A4[1];
      Ar[0]=v0.x*LOG2E; Ar[1]=v0.y*LOG2E; Ar[2]=v0.z*LOG2E; Ar[3]=v0.w*LOG2E;
      Ar[4]=v1.x*LOG2E; Ar[5]=v1.y*LOG2E; Ar[6]=v1.z*LOG2E; Ar[7]=v1.w*LOG2E;
    }
    const float4* B4 = reinterpret_cast<const float4*>(Bm + ((size_t)b * kN + half * NH) * kL);
    const float4* C4 = reinterpret_cast<const float4*>(Cm + ((size_t)b * kN + half * NH) * kL);

    // ---- Pass A with the cp-trick: C consumed at load time.
    // h_i = pp_i*h0 + hl_i (linearity) =>  y_i += C_i*hl_i here,
    // cp_i = C_i*pp_i saved; post-scan apply is pure register FMA.
    float cp[NH][T];
    float cA[NH], cX[NH];
    #pragma unroll
    for (int n = 0; n < NH; ++n) {
      float4 b0 = B4[n*(kL/4) + tid];
      float4 c0 = C4[n*(kL/4) + tid];
      float Bv[T] = {b0.x, b0.y, b0.z, b0.w};
      float Cv[T] = {c0.x, c0.y, c0.z, c0.w};
      float h = 0.0f, p = 1.0f;
      #pragma unroll
      for (int i = 0; i < T; ++i) {
        float a = fast_exp2(sp[i] * Ar[n]);
        h = a * h + du[i] * Bv[i];
        p *= a;
        y[i] += Cv[i] * h;
        cp[n][i] = Cv[i] * p;
      }
      cA[n] = p; cX[n] = h;
    }

    // ---- Wave-level scan on chunk aggregates — raw DPP, 2 inst/state/step.
    {
      float x0=cX[0], x1=cX[1], x2=cX[2], x3=cX[3],
            x4=cX[4], x5=cX[5], x6=cX[6], x7=cX[7];
      float a0=cA[0], a1=cA[1], a2=cA[2], a3=cA[3],
            a4=cA[4], a5=cA[5], a6=cA[6], a7=cA[7];
      asm("s_nop 1\n\t"
          SCAN_STEP("row_shr:1 row_mask:0xf bank_mask:0xf")
          SCAN_STEP("row_shr:2 row_mask:0xf bank_mask:0xf")
          SCAN_STEP("row_shr:4 row_mask:0xf bank_mask:0xf")
          SCAN_STEP("row_shr:8 row_mask:0xf bank_mask:0xf")
          SCAN_STEP("row_bcast:15 row_mask:0xa bank_mask:0xf")
          SCAN_STEP("row_bcast:31 row_mask:0xc bank_mask:0xf")
          : "+v"(x0), "+v"(x1), "+v"(x2), "+v"(x3),
            "+v"(x4), "+v"(x5), "+v"(x6), "+v"(x7),
            "+v"(a0), "+v"(a1), "+v"(a2), "+v"(a3),
            "+v"(a4), "+v"(a5), "+v"(a6), "+v"(a7));
      cX[0]=x0; cX[1]=x1; cX[2]=x2; cX[3]=x3;
      cX[4]=x4; cX[5]=x5; cX[6]=x6; cX[7]=x7;
      cA[0]=a0; cA[1]=a1; cA[2]=a2; cA[3]=a3;
      cA[4]=a4; cA[5]=a5; cA[6]=a6; cA[7]=a7;
    }

    // ---- Publish wave totals (lane 63 holds them), ONE barrier, then every
    // wave folds its OWN exclusive prefix (<=7 chained FMAs, all waves in
    // parallel — replaces R12's single-wave serial section + 2nd barrier).
    // Side-effect: wave w exits ~w fold-steps later -> natural desync.
    if (lane == 63) {
      #pragma unroll
      for (int n = 0; n < NH; ++n) sAX[half][wid][n] = make_float2(cA[n], cX[n]);
    }
    __syncthreads();

    float ex = 0.0f;                     // lane n<8: exclusive x-prefix, state n
    {
      const int n = lane & 7;
      for (int w2 = 0; w2 < wid; ++w2) { // wid uniform per wave: no divergence
        float2 s = sAX[half][w2][n];
        ex = s.x * ex + s.y;
      }
    }

    // ---- Apply: y_i += cp_i * h0   (pure FMA; eX broadcast via readlane)
    #pragma unroll
    for (int n = 0; n < NH; ++n) {
      float al = dppf<0x138,0xF>(1.0f, cA[n]);   // lane-exclusive prefix
      float xl = dppf<0x138,0xF>(0.0f, cX[n]);
      float exn = readlane_f(ex, n);             // scalar: wave-exclusive x
      float h0 = al * exn + xl;                  // state entering this chunk
      #pragma unroll
      for (int i = 0; i < T; ++i) y[i] += cp[n][i] * h0;
    }
    // no end-of-half barrier: half 1 uses its own sAX buffer
  }

  // ---- Epilogue: + u*D, * silu(z), store  (uu kept in regs)
  const float Dd = Dv[d];
  const float4* z4 = reinterpret_cast<const float4*>(zm + roff);
  float4 z0 = z4[tid];
  float zv[T] = {z0.x, z0.y, z0.z, z0.w};
  float ov[T];
  #pragma unroll
  for (int i = 0; i < T; ++i) {
    float yy  = y[i] + uu[i] * Dd;
    float sig = 1.0f / (1.0f + fast_exp(-zv[i]));
    ov[i] = yy * zv[i] * sig;
  }
  reinterpret_cast<float4*>(out + roff)[tid] = make_float4(ov[0], ov[1], ov[2], ov[3]);
}

extern "C" void kernel_launch(void* const* d_in, const int* in_sizes, int n_in,
                              void* d_out, int out_size, void* d_ws, size_t ws_size,
                              hipStream_t stream)
{
  const float* u  = (const float*)d_in[0];
  const float* dl = (const float*)d_in[1];
  const float* A  = (const float*)d_in[2];
  const float* Bm = (const float*)d_in[3];
  const float* Cm = (const float*)d_in[4];
  const float* Dv = (const float*)d_in[5];
  const float* zm = (const float*)d_in[6];
  float* out = (float*)d_out;
  const int rows = in_sizes[0] / kL;   // b*d = 2048
  selscan_kernel<<<rows, BLOCK, 0, stream>>>(u, dl, A, Bm, Cm, Dv, zm, out);
}